// Round 3
// baseline (415.418 us; speedup 1.0000x reference)
//
#include <hip/hip_runtime.h>

// PLoss fused kernel, round 5.
// Round-4 post-mortem: 298.3 us total; fills = ~240 us fixed; ploss_main ~53 us
// vs 33 us HBM floor. Remaining cost: x f32->LDS->ds_read round trip (128 VALU
// RTNE pack + 4 ds_write + lgkmcnt(0) + 4 ds_read per tile-wave), ~190 VALU of
// f2ord argmin packing, and occupancy capped at 3 blocks/CU.
// Changes this round:
//  - x loaded DIRECTLY in MFMA-A fragment layout (lane <- row l15, cols
//    kt*32+quad*8): no x_lds, no pack-to-LDS, no waitcnt fence. Softmax
//    reduces over the quad axis (shfl 16/32); lse stays in-register.
//  - A fragments built in-register with native __bf16 casts (compiler cvt_pk).
//  - Epilogue gathers x[row][eff] as a single f32 scalar global load
//    (L1/L2-hit; exact f32, better than old bf16 LDS gather).
//  - argmin score = d^2/2 = 0.5||x||^2 + 0.5||p||^2 - x.p  >= 0 -> uint
//    compare without sign-flip transform (~3 VALU/candidate, was 6).
//    Row norm 0.5||x||^2 computed during the softmax pass (quad-reduce).
//  - MFMA in 2 passes of 4 n-tiles: acc 32->16 VGPR; peak pressure ~112 VGPR
//    -> __launch_bounds__(256,4) -> 4 blocks/CU (LDS now 33.3 KB). grid=1024
//    (exactly resident, one generation, prologue amortized over ~6 tiles).

#define C_DIM 128
#define TILE_ROWS 64
#define NTHREADS 256
#define GRID_MAX 1024
#define NFRAG 32              // 8 n-tiles * 4 k-tiles

typedef __bf16 bf16x8 __attribute__((ext_vector_type(8)));
typedef unsigned short ushort8 __attribute__((ext_vector_type(8)));
typedef float f32x4 __attribute__((ext_vector_type(4)));

union FragU { ushort8 u; bf16x8 b; };

__device__ __forceinline__ unsigned short f2bf(float f) {   // prologue staging only
    unsigned int u = __float_as_uint(f);
    u += 0x7fffu + ((u >> 16) & 1u);   // round-to-nearest-even
    return (unsigned short)(u >> 16);
}
__device__ __forceinline__ float fmax4(float4 v) {
    return fmaxf(fmaxf(v.x, v.y), fmaxf(v.z, v.w));
}
__device__ __forceinline__ float esum4(float4 v, float m) {
    return __expf(v.x - m) + __expf(v.y - m) + __expf(v.z - m) + __expf(v.w - m);
}
__device__ __forceinline__ float dot4(float4 v) {
    return v.x*v.x + v.y*v.y + v.z*v.z + v.w*v.w;
}
__device__ __forceinline__ bf16x8 cvt8(float4 lo, float4 hi) {
    bf16x8 r;
    r[0]=(__bf16)lo.x; r[1]=(__bf16)lo.y; r[2]=(__bf16)lo.z; r[3]=(__bf16)lo.w;
    r[4]=(__bf16)hi.x; r[5]=(__bf16)hi.y; r[6]=(__bf16)hi.z; r[7]=(__bf16)hi.w;
    return r;
}

extern "C" __global__ void __launch_bounds__(NTHREADS, 4)
ploss_main(const float* __restrict__ x, const int* __restrict__ labels,
           const float* __restrict__ protos, const int* __restrict__ kptr,
           float* __restrict__ partial, int n_tiles, int n_rows)
{
    // 32768 + 512 + 16 = 33.3 KB -> 4 blocks/CU (needs VGPR <= 128)
    __shared__ __attribute__((aligned(16))) unsigned short blds[NFRAG * 64 * 8];
    __shared__ float norm_lds[C_DIM];
    __shared__ float wsum[4];

    const int tid  = threadIdx.x;
    const int lane = tid & 63;
    const int wave = tid >> 6;
    const int l15  = lane & 15;
    const int quad = lane >> 4;
    const int wrow = wave * 16;
    const int kk   = kptr[0];

    // ---- prologue: proto squared norms (2 threads per proto) ----
    {
        const int j = tid >> 1;
        const float* pr = protos + j * C_DIM + (tid & 1) * 64;
        float s = 0.f;
#pragma unroll
        for (int c = 0; c < 64; c += 4) {
            float4 v = *(const float4*)(pr + c);
            s += dot4(v);
        }
        s += __shfl_xor(s, 1);
        if ((tid & 1) == 0) norm_lds[j] = s;
    }
    // ---- prologue: protos -> frag-linear bf16 MFMA-B fragments in LDS ----
    // frag id = nt*4+kt; lane l holds col nt*16+(l&15), k = kt*32+(l>>4)*8..+8
#pragma unroll
    for (int f = 0; f < 8; ++f) {
        const int g = f * NTHREADS + tid;       // 0..2047 = frag*64 + lane
        const int l = g & 63;
        const int frag = g >> 6;
        const int nt = frag >> 2, kt = frag & 3;
        const float* pp = protos + (nt * 16 + (l & 15)) * C_DIM + kt * 32 + (l >> 4) * 8;
        float4 v0 = *(const float4*)(pp);
        float4 v1 = *(const float4*)(pp + 4);
        FragU fr;
        fr.u[0]=f2bf(v0.x); fr.u[1]=f2bf(v0.y); fr.u[2]=f2bf(v0.z); fr.u[3]=f2bf(v0.w);
        fr.u[4]=f2bf(v1.x); fr.u[5]=f2bf(v1.y); fr.u[6]=f2bf(v1.z); fr.u[7]=f2bf(v1.w);
        *(ushort8*)&blds[g * 8] = fr.u;
    }
    __syncthreads();   // blds + norm_lds ready; no further barriers until reduce

    float p2h[8];
#pragma unroll
    for (int nt = 0; nt < 8; ++nt) p2h[nt] = 0.5f * norm_lds[nt * 16 + l15];

    float nll_acc = 0.f;

    // ---- prologue: first tile, loaded in A-fragment layout ----
    // lane (quad,l15): row = tilebase + wrow + l15, cols kt*32 + quad*8 + 0..7
    int t = blockIdx.x;
    float4 a[8];
    int lab = 0;
    {
        long long rb = (long long)t * TILE_ROWS + wrow + l15;
        if (rb >= n_rows) rb = n_rows - 1;
        const float* xr = x + rb * C_DIM;
#pragma unroll
        for (int i = 0; i < 8; ++i)
            a[i] = *(const float4*)(xr + (i >> 1) * 32 + quad * 8 + (i & 1) * 4);
        if (l15 < 4) {
            long long lb = (long long)t * TILE_ROWS + wrow + quad * 4 + l15;
            if (lb >= n_rows) lb = n_rows - 1;
            lab = labels[lb];
        }
    }

    for (; t < n_tiles; t += gridDim.x) {
        // ---- prefetch next tile (x + labels) into shadow registers ----
        const int tn = t + gridDim.x;
        const int tl = (tn < n_tiles) ? tn : t;    // clamp: tail load discarded
        float4 b[8];
        int labn = lab;
        {
            long long rb = (long long)tl * TILE_ROWS + wrow + l15;
            if (rb >= n_rows) rb = n_rows - 1;
            const float* xr = x + rb * C_DIM;
#pragma unroll
            for (int i = 0; i < 8; ++i)
                b[i] = *(const float4*)(xr + (i >> 1) * 32 + quad * 8 + (i & 1) * 4);
            if (l15 < 4) {
                long long lb = (long long)tl * TILE_ROWS + wrow + quad * 4 + l15;
                if (lb >= n_rows) lb = n_rows - 1;
                labn = labels[lb];
            }
        }

        // ---- row stats (reduce over quad axis: masks 16, 32) ----
        float m = fmax4(a[0]);
#pragma unroll
        for (int i = 1; i < 8; ++i) m = fmaxf(m, fmax4(a[i]));
        m = fmaxf(m, __shfl_xor(m, 16));
        m = fmaxf(m, __shfl_xor(m, 32));
        float s = 0.f, h2 = 0.f;
#pragma unroll
        for (int i = 0; i < 8; ++i) { s += esum4(a[i], m); h2 += dot4(a[i]); }
        s  += __shfl_xor(s, 16);  h2 += __shfl_xor(h2, 16);
        s  += __shfl_xor(s, 32);  h2 += __shfl_xor(h2, 32);
        const float lse = m + __logf(s);
        h2 *= 0.5f;                          // 0.5*||x_row||^2, row = l15

        // ---- A fragments: in-register bf16 convert (no LDS round trip) ----
        FragU A[4];
#pragma unroll
        for (int kt = 0; kt < 4; ++kt) A[kt].b = cvt8(a[2 * kt], a[2 * kt + 1]);

        // per-acc-row constants: acc C-row = quad*4+rg, its h2 lives in lane row
        float hp[4];
#pragma unroll
        for (int rg = 0; rg < 4; ++rg) hp[rg] = __shfl(h2, quad * 4 + rg);
        const float lse_r = __shfl(lse, quad * 4 + l15);  // epilogue lse (l15<4)

        // ---- MFMA + packed argmin, 2 passes of 4 n-tiles (acc = 16 VGPR) ----
        unsigned um0 = 0xFFFFFFFFu, um1 = 0xFFFFFFFFu,
                 um2 = 0xFFFFFFFFu, um3 = 0xFFFFFFFFu;
#pragma unroll
        for (int pass = 0; pass < 2; ++pass) {
            f32x4 acc[4];
            f32x4 zero = {0.f, 0.f, 0.f, 0.f};
#pragma unroll
            for (int nti = 0; nti < 4; ++nti) acc[nti] = zero;
#pragma unroll
            for (int kt = 0; kt < 4; ++kt) {
#pragma unroll
                for (int nti = 0; nti < 4; ++nti) {
                    const int nt = pass * 4 + nti;
                    FragU B;
                    B.u = *(const ushort8*)&blds[((nt * 4 + kt) * 64 + lane) * 8];
                    acc[nti] = __builtin_amdgcn_mfma_f32_16x16x32_bf16(
                                   A[kt].b, B.b, acc[nti], 0, 0, 0);
                }
            }
            // score = d^2/2 = h2(row) + p2h(col) - x.p  (>= 0 -> uint-ordered)
#pragma unroll
            for (int nti = 0; nti < 4; ++nti) {
                const int nt = pass * 4 + nti;
                const unsigned idx = (unsigned)(nt * 16 + l15);
                {
                    unsigned c = (__float_as_uint((hp[0] + p2h[nt]) - acc[nti][0]) & 0xFFFFFF80u) | idx;
                    um0 = c < um0 ? c : um0;
                }
                {
                    unsigned c = (__float_as_uint((hp[1] + p2h[nt]) - acc[nti][1]) & 0xFFFFFF80u) | idx;
                    um1 = c < um1 ? c : um1;
                }
                {
                    unsigned c = (__float_as_uint((hp[2] + p2h[nt]) - acc[nti][2]) & 0xFFFFFF80u) | idx;
                    um2 = c < um2 ? c : um2;
                }
                {
                    unsigned c = (__float_as_uint((hp[3] + p2h[nt]) - acc[nti][3]) & 0xFFFFFF80u) | idx;
                    um3 = c < um3 ? c : um3;
                }
            }
        }
        // cross-l15 reduce (masks 1..8 stay within the 16-lane quad group)
#pragma unroll
        for (int mask = 1; mask <= 8; mask <<= 1) {
            unsigned o0 = __shfl_xor(um0, mask); um0 = o0 < um0 ? o0 : um0;
            unsigned o1 = __shfl_xor(um1, mask); um1 = o1 < um1 ? o1 : um1;
            unsigned o2 = __shfl_xor(um2, mask); um2 = o2 < um2 ? o2 : um2;
            unsigned o3 = __shfl_xor(um3, mask); um3 = o3 < um3 ? o3 : um3;
        }
        const int rs = l15 & 3;
        const unsigned ur = rs == 0 ? um0 : rs == 1 ? um1 : rs == 2 ? um2 : um3;

        // ---- epilogue: 16 lanes/wave, one row each; f32 scalar gather ----
        if (l15 < 4) {
            const long long grow = (long long)t * TILE_ROWS + wrow + quad * 4 + l15;
            if (grow < n_rows) {
                const int bj  = (int)(ur & 127u);
                const int eff = (lab <= kk - 1) ? lab : bj;
                const float xv = x[grow * C_DIM + eff];   // L1/L2 hit (just streamed)
                nll_acc += lse_r - xv;
            }
        }

        // rotate prefetch buffers
#pragma unroll
        for (int i = 0; i < 8; ++i) a[i] = b[i];
        lab = labn;
    }

    // ---- block reduce -> per-block partial (no atomics, no memset) ----
    float v = nll_acc;
#pragma unroll
    for (int mask = 1; mask <= 32; mask <<= 1) v += __shfl_xor(v, mask);
    if (lane == 0) wsum[wave] = v;
    __syncthreads();
    if (tid == 0) partial[blockIdx.x] = wsum[0] + wsum[1] + wsum[2] + wsum[3];
}

extern "C" __global__ void __launch_bounds__(256)
ploss_finalize(const float* __restrict__ partial, float* __restrict__ out,
               float inv_n, int nparts)
{
    __shared__ double sm[4];
    const int tid = threadIdx.x, lane = tid & 63, wave = tid >> 6;
    double v = 0.0;
    for (int i = tid; i < nparts; i += 256) v += (double)partial[i];
#pragma unroll
    for (int mask = 1; mask <= 32; mask <<= 1) v += __shfl_xor(v, mask);
    if (lane == 0) sm[wave] = v;
    __syncthreads();
    if (tid == 0) out[0] = (float)((sm[0] + sm[1] + sm[2] + sm[3]) * (double)inv_n);
}

extern "C" void kernel_launch(void* const* d_in, const int* in_sizes, int n_in,
                              void* d_out, int out_size, void* d_ws, size_t ws_size,
                              hipStream_t stream)
{
    const float* x      = (const float*)d_in[0];
    const int*   labels = (const int*)d_in[1];
    const float* protos = (const float*)d_in[2];
    const int*   kptr   = (const int*)d_in[3];
    const int n_rows  = in_sizes[0] / C_DIM;                 // element counts
    const int n_tiles = (n_rows + TILE_ROWS - 1) / TILE_ROWS; // 400000/64 = 6250

    float* partial = (float*)d_ws;   // overwritten every call; poison-safe

    int grid = GRID_MAX;
    if (grid > n_tiles) grid = n_tiles;
    const int max_parts = (int)(ws_size / sizeof(float));    // workspace guard
    if (grid > max_parts) grid = max_parts;
    if (grid < 1) grid = 1;

    ploss_main<<<grid, NTHREADS, 0, stream>>>(x, labels, protos, kptr, partial,
                                              n_tiles, n_rows);
    ploss_finalize<<<1, 256, 0, stream>>>(partial, (float*)d_out,
                                          1.0f / (float)n_rows, grid);
}

// Round 4
// 400.052 us; speedup vs baseline: 1.0384x; 1.0384x over previous
//
#include <hip/hip_runtime.h>

// PLoss fused kernel, round 6.
// Round-5 post-mortem: 415 us total, ploss_main 226 us. Counters: VGPR_Count=64,
// WRITE_SIZE=148.5 MB (legit writes ~6 KB!), FETCH=563 MB vs 205 MB mandatory
// -> the a[8]+b[8] double-buffer (64 VGPR) + frags/acc exceeded the 64-VGPR
// allocation the compiler chose under __launch_bounds__(256,4); the prefetch
// buffer spilled to scratch every iteration. Spill round-trips = the regression.
// Fix this round (ONLY the register budget changes; algorithm identical):
//  - __launch_bounds__(256,3): VGPR cap ~168 >> ~110 peak live -> no spills.
//    LDS 33.8 KB still allows 4 blocks/CU if the allocator lands <=128.
//  - grid back to 1536 for load-balance granularity (ws guard retained).
// Structure retained from round 5:
//  - x loaded directly in MFMA-A fragment layout; softmax/h2 reduce over quad
//    axis (shfl 16/32); lse in-register; no x_lds, no pack, no fences,
//    no per-tile barriers.
//  - argmin score d^2/2 = 0.5||x||^2 + 0.5||p||^2 - x.p >= 0 -> plain uint
//    min with 7-bit index in low mantissa bits; 8 in-reg candidates + 4 shfl.
//  - MFMA in 2 passes of 4 n-tiles (acc 16 VGPR live).
//  - Epilogue: one f32 scalar gather x[row][eff] (L1/L2 hit, exact).
//  - partial[blockIdx] overwrite; finalize sums in double.

#define C_DIM 128
#define TILE_ROWS 64
#define NTHREADS 256
#define GRID_MAX 1536
#define NFRAG 32              // 8 n-tiles * 4 k-tiles

typedef __bf16 bf16x8 __attribute__((ext_vector_type(8)));
typedef unsigned short ushort8 __attribute__((ext_vector_type(8)));
typedef float f32x4 __attribute__((ext_vector_type(4)));

union FragU { ushort8 u; bf16x8 b; };

__device__ __forceinline__ unsigned short f2bf(float f) {   // prologue staging only
    unsigned int u = __float_as_uint(f);
    u += 0x7fffu + ((u >> 16) & 1u);   // round-to-nearest-even
    return (unsigned short)(u >> 16);
}
__device__ __forceinline__ float fmax4(float4 v) {
    return fmaxf(fmaxf(v.x, v.y), fmaxf(v.z, v.w));
}
__device__ __forceinline__ float esum4(float4 v, float m) {
    return __expf(v.x - m) + __expf(v.y - m) + __expf(v.z - m) + __expf(v.w - m);
}
__device__ __forceinline__ float dot4(float4 v) {
    return v.x*v.x + v.y*v.y + v.z*v.z + v.w*v.w;
}
__device__ __forceinline__ bf16x8 cvt8(float4 lo, float4 hi) {
    bf16x8 r;
    r[0]=(__bf16)lo.x; r[1]=(__bf16)lo.y; r[2]=(__bf16)lo.z; r[3]=(__bf16)lo.w;
    r[4]=(__bf16)hi.x; r[5]=(__bf16)hi.y; r[6]=(__bf16)hi.z; r[7]=(__bf16)hi.w;
    return r;
}

extern "C" __global__ void __launch_bounds__(NTHREADS, 3)
ploss_main(const float* __restrict__ x, const int* __restrict__ labels,
           const float* __restrict__ protos, const int* __restrict__ kptr,
           float* __restrict__ partial, int n_tiles, int n_rows)
{
    // 32768 + 512 + 16 = 33.3 KB
    __shared__ __attribute__((aligned(16))) unsigned short blds[NFRAG * 64 * 8];
    __shared__ float norm_lds[C_DIM];
    __shared__ float wsum[4];

    const int tid  = threadIdx.x;
    const int lane = tid & 63;
    const int wave = tid >> 6;
    const int l15  = lane & 15;
    const int quad = lane >> 4;
    const int wrow = wave * 16;
    const int kk   = kptr[0];

    // ---- prologue: proto squared norms (2 threads per proto) ----
    {
        const int j = tid >> 1;
        const float* pr = protos + j * C_DIM + (tid & 1) * 64;
        float s = 0.f;
#pragma unroll
        for (int c = 0; c < 64; c += 4) {
            float4 v = *(const float4*)(pr + c);
            s += dot4(v);
        }
        s += __shfl_xor(s, 1);
        if ((tid & 1) == 0) norm_lds[j] = s;
    }
    // ---- prologue: protos -> frag-linear bf16 MFMA-B fragments in LDS ----
    // frag id = nt*4+kt; lane l holds col nt*16+(l&15), k = kt*32+(l>>4)*8..+8
#pragma unroll
    for (int f = 0; f < 8; ++f) {
        const int g = f * NTHREADS + tid;       // 0..2047 = frag*64 + lane
        const int l = g & 63;
        const int frag = g >> 6;
        const int nt = frag >> 2, kt = frag & 3;
        const float* pp = protos + (nt * 16 + (l & 15)) * C_DIM + kt * 32 + (l >> 4) * 8;
        float4 v0 = *(const float4*)(pp);
        float4 v1 = *(const float4*)(pp + 4);
        FragU fr;
        fr.u[0]=f2bf(v0.x); fr.u[1]=f2bf(v0.y); fr.u[2]=f2bf(v0.z); fr.u[3]=f2bf(v0.w);
        fr.u[4]=f2bf(v1.x); fr.u[5]=f2bf(v1.y); fr.u[6]=f2bf(v1.z); fr.u[7]=f2bf(v1.w);
        *(ushort8*)&blds[g * 8] = fr.u;
    }
    __syncthreads();   // blds + norm_lds ready; no further barriers until reduce

    float p2h[8];
#pragma unroll
    for (int nt = 0; nt < 8; ++nt) p2h[nt] = 0.5f * norm_lds[nt * 16 + l15];

    float nll_acc = 0.f;

    // ---- prologue: first tile, loaded in A-fragment layout ----
    // lane (quad,l15): row = tilebase + wrow + l15, cols kt*32 + quad*8 + 0..7
    int t = blockIdx.x;
    float4 a[8];
    int lab = 0;
    {
        long long rb = (long long)t * TILE_ROWS + wrow + l15;
        if (rb >= n_rows) rb = n_rows - 1;
        const float* xr = x + rb * C_DIM;
#pragma unroll
        for (int i = 0; i < 8; ++i)
            a[i] = *(const float4*)(xr + (i >> 1) * 32 + quad * 8 + (i & 1) * 4);
        if (l15 < 4) {
            long long lb = (long long)t * TILE_ROWS + wrow + quad * 4 + l15;
            if (lb >= n_rows) lb = n_rows - 1;
            lab = labels[lb];
        }
    }

    for (; t < n_tiles; t += gridDim.x) {
        // ---- prefetch next tile (x + labels) into shadow registers ----
        const int tn = t + gridDim.x;
        const int tl = (tn < n_tiles) ? tn : t;    // clamp: tail load discarded
        float4 b[8];
        int labn = lab;
        {
            long long rb = (long long)tl * TILE_ROWS + wrow + l15;
            if (rb >= n_rows) rb = n_rows - 1;
            const float* xr = x + rb * C_DIM;
#pragma unroll
            for (int i = 0; i < 8; ++i)
                b[i] = *(const float4*)(xr + (i >> 1) * 32 + quad * 8 + (i & 1) * 4);
            if (l15 < 4) {
                long long lb = (long long)tl * TILE_ROWS + wrow + quad * 4 + l15;
                if (lb >= n_rows) lb = n_rows - 1;
                labn = labels[lb];
            }
        }

        // ---- row stats (reduce over quad axis: masks 16, 32) ----
        float m = fmax4(a[0]);
#pragma unroll
        for (int i = 1; i < 8; ++i) m = fmaxf(m, fmax4(a[i]));
        m = fmaxf(m, __shfl_xor(m, 16));
        m = fmaxf(m, __shfl_xor(m, 32));
        float s = 0.f, h2 = 0.f;
#pragma unroll
        for (int i = 0; i < 8; ++i) { s += esum4(a[i], m); h2 += dot4(a[i]); }
        s  += __shfl_xor(s, 16);  h2 += __shfl_xor(h2, 16);
        s  += __shfl_xor(s, 32);  h2 += __shfl_xor(h2, 32);
        const float lse = m + __logf(s);
        h2 *= 0.5f;                          // 0.5*||x_row||^2, row = l15

        // ---- A fragments: in-register bf16 convert (a[] dies here) ----
        FragU A[4];
#pragma unroll
        for (int kt = 0; kt < 4; ++kt) A[kt].b = cvt8(a[2 * kt], a[2 * kt + 1]);

        // per-acc-row constants: acc C-row = quad*4+rg, its h2 lives in lane row
        float hp[4];
#pragma unroll
        for (int rg = 0; rg < 4; ++rg) hp[rg] = __shfl(h2, quad * 4 + rg);
        const float lse_r = __shfl(lse, quad * 4 + l15);  // epilogue lse (l15<4)

        // ---- MFMA + packed argmin, 2 passes of 4 n-tiles (acc = 16 VGPR) ----
        unsigned um0 = 0xFFFFFFFFu, um1 = 0xFFFFFFFFu,
                 um2 = 0xFFFFFFFFu, um3 = 0xFFFFFFFFu;
#pragma unroll
        for (int pass = 0; pass < 2; ++pass) {
            f32x4 acc[4];
            f32x4 zero = {0.f, 0.f, 0.f, 0.f};
#pragma unroll
            for (int nti = 0; nti < 4; ++nti) acc[nti] = zero;
#pragma unroll
            for (int kt = 0; kt < 4; ++kt) {
#pragma unroll
                for (int nti = 0; nti < 4; ++nti) {
                    const int nt = pass * 4 + nti;
                    FragU B;
                    B.u = *(const ushort8*)&blds[((nt * 4 + kt) * 64 + lane) * 8];
                    acc[nti] = __builtin_amdgcn_mfma_f32_16x16x32_bf16(
                                   A[kt].b, B.b, acc[nti], 0, 0, 0);
                }
            }
            // score = d^2/2 = h2(row) + p2h(col) - x.p  (>= 0 -> uint-ordered)
#pragma unroll
            for (int nti = 0; nti < 4; ++nti) {
                const int nt = pass * 4 + nti;
                const unsigned idx = (unsigned)(nt * 16 + l15);
                {
                    unsigned c = (__float_as_uint((hp[0] + p2h[nt]) - acc[nti][0]) & 0xFFFFFF80u) | idx;
                    um0 = c < um0 ? c : um0;
                }
                {
                    unsigned c = (__float_as_uint((hp[1] + p2h[nt]) - acc[nti][1]) & 0xFFFFFF80u) | idx;
                    um1 = c < um1 ? c : um1;
                }
                {
                    unsigned c = (__float_as_uint((hp[2] + p2h[nt]) - acc[nti][2]) & 0xFFFFFF80u) | idx;
                    um2 = c < um2 ? c : um2;
                }
                {
                    unsigned c = (__float_as_uint((hp[3] + p2h[nt]) - acc[nti][3]) & 0xFFFFFF80u) | idx;
                    um3 = c < um3 ? c : um3;
                }
            }
        }
        // cross-l15 reduce (masks 1..8 stay within the 16-lane quad group)
#pragma unroll
        for (int mask = 1; mask <= 8; mask <<= 1) {
            unsigned o0 = __shfl_xor(um0, mask); um0 = o0 < um0 ? o0 : um0;
            unsigned o1 = __shfl_xor(um1, mask); um1 = o1 < um1 ? o1 : um1;
            unsigned o2 = __shfl_xor(um2, mask); um2 = o2 < um2 ? o2 : um2;
            unsigned o3 = __shfl_xor(um3, mask); um3 = o3 < um3 ? o3 : um3;
        }
        const int rs = l15 & 3;
        const unsigned ur = rs == 0 ? um0 : rs == 1 ? um1 : rs == 2 ? um2 : um3;

        // ---- epilogue: 16 lanes/wave, one row each; f32 scalar gather ----
        if (l15 < 4) {
            const long long grow = (long long)t * TILE_ROWS + wrow + quad * 4 + l15;
            if (grow < n_rows) {
                const int bj  = (int)(ur & 127u);
                const int eff = (lab <= kk - 1) ? lab : bj;
                const float xv = x[grow * C_DIM + eff];   // L1/L2 hit (just streamed)
                nll_acc += lse_r - xv;
            }
        }

        // rotate prefetch buffers
#pragma unroll
        for (int i = 0; i < 8; ++i) a[i] = b[i];
        lab = labn;
    }

    // ---- block reduce -> per-block partial (no atomics, no memset) ----
    float v = nll_acc;
#pragma unroll
    for (int mask = 1; mask <= 32; mask <<= 1) v += __shfl_xor(v, mask);
    if (lane == 0) wsum[wave] = v;
    __syncthreads();
    if (tid == 0) partial[blockIdx.x] = wsum[0] + wsum[1] + wsum[2] + wsum[3];
}

extern "C" __global__ void __launch_bounds__(256)
ploss_finalize(const float* __restrict__ partial, float* __restrict__ out,
               float inv_n, int nparts)
{
    __shared__ double sm[4];
    const int tid = threadIdx.x, lane = tid & 63, wave = tid >> 6;
    double v = 0.0;
    for (int i = tid; i < nparts; i += 256) v += (double)partial[i];
#pragma unroll
    for (int mask = 1; mask <= 32; mask <<= 1) v += __shfl_xor(v, mask);
    if (lane == 0) sm[wave] = v;
    __syncthreads();
    if (tid == 0) out[0] = (float)((sm[0] + sm[1] + sm[2] + sm[3]) * (double)inv_n);
}

extern "C" void kernel_launch(void* const* d_in, const int* in_sizes, int n_in,
                              void* d_out, int out_size, void* d_ws, size_t ws_size,
                              hipStream_t stream)
{
    const float* x      = (const float*)d_in[0];
    const int*   labels = (const int*)d_in[1];
    const float* protos = (const float*)d_in[2];
    const int*   kptr   = (const int*)d_in[3];
    const int n_rows  = in_sizes[0] / C_DIM;                 // element counts
    const int n_tiles = (n_rows + TILE_ROWS - 1) / TILE_ROWS; // 400000/64 = 6250

    float* partial = (float*)d_ws;   // overwritten every call; poison-safe

    int grid = GRID_MAX;
    if (grid > n_tiles) grid = n_tiles;
    const int max_parts = (int)(ws_size / sizeof(float));    // workspace guard
    if (grid > max_parts) grid = max_parts;
    if (grid < 1) grid = 1;

    ploss_main<<<grid, NTHREADS, 0, stream>>>(x, labels, protos, kptr, partial,
                                              n_tiles, n_rows);
    ploss_finalize<<<1, 256, 0, stream>>>(partial, (float*)d_out,
                                          1.0f / (float)n_rows, grid);
}